// Round 8
// baseline (331.864 us; speedup 1.0000x reference)
//
#include <hip/hip_runtime.h>

typedef _Float16 half8 __attribute__((ext_vector_type(8)));
typedef _Float16 half4 __attribute__((ext_vector_type(4)));
typedef float f32x4 __attribute__((ext_vector_type(4)));

#define T_STEPS 256
#define NB      32           // 2 independent 16-batch groups per block
#define NBLOCKS (4096/NB)    // 128 blocks, 1 per CU (half the CUs idle, but
                             // each CU advances 2 recurrences per interval)
#define LOG2E   1.4426950408889634f

// merged activation buffer stride (f16 units): cols 0..63 = h1, 64..127 = h2.
// 136 = 8*17 -> b128 reads conflict-free ((ln+lb)%8 chunk permutation).
#define SH 136

__device__ __forceinline__ half8 cvt8s(const float* __restrict__ p, float s) {
    half8 r;
    #pragma unroll
    for (int j = 0; j < 8; ++j) r[j] = (_Float16)(p[j] * s);
    return r;
}

// LDS-only barrier: does NOT drain vmcnt, so global x prefetch stays in flight.
__device__ __forceinline__ void sync_lds() {
    asm volatile("s_waitcnt lgkmcnt(0)" ::: "memory");
    __builtin_amdgcn_s_barrier();
}

// 512 threads, min 2 waves/EU -> reg cap 256 (fits ~185, no spill).
__global__ __launch_bounds__(512, 2)
void lstm_v8(const float* __restrict__ x,
             const float* __restrict__ Wih0, const float* __restrict__ Whh0,
             const float* __restrict__ bih0, const float* __restrict__ bhh0,
             const float* __restrict__ Wih1, const float* __restrict__ Whh1,
             const float* __restrict__ bih1, const float* __restrict__ bhh1,
             const float* __restrict__ Wout, const float* __restrict__ bout,
             float* __restrict__ out)
{
    __shared__ _Float16 HbA[2][16][SH];   // group A: batches gb0 + 0..15
    __shared__ _Float16 HbB[2][16][SH];   // group B: batches gb0 + 16..31

    const int tid  = threadIdx.x;
    const int w    = tid >> 6;
    const bool isL1 = (w < 4);          // waves 0-3: layer 1; waves 4-7: layer 2
    const int wq   = w & 3;
    const int l    = tid & 63;
    const int ln   = l & 15;            // weight row (A) / batch col (B)
    const int lb   = l >> 4;            // k sub-block / C-row group
    const int ub   = 16 * wq + 4 * lb;  // first unit this lane's acc covers
    const int gb0  = blockIdx.x * NB;

    // ---- weight A-fragments, register-resident, sign/scale pre-folded ----
    // gate q scale: i,f,o -> -log2e (exp2(acc) = e^{-raw}); g -> +2*log2e.
    // L1: wa[q][0] = x-slice (K 0..31), wa[q][1..2] = h1-slices; [3] unused.
    // L2: wa[q][0..3] = [h1 | h2] K-slices.
    half8 wa[4][4];
    f32x4 bv[4];
    if (isL1) {
        #pragma unroll
        for (int q = 0; q < 4; ++q) {
            const float s = (q == 2) ? 2.f * LOG2E : -LOG2E;
            const int g = 64 * q + 16 * wq + ln;
            wa[q][0] = cvt8s(Wih0 + g * 32 + 8 * lb, s);
            #pragma unroll
            for (int ks = 0; ks < 2; ++ks)
                wa[q][1 + ks] = cvt8s(Whh0 + g * 64 + 32 * ks + 8 * lb, s);
            #pragma unroll
            for (int jj = 0; jj < 4; ++jj) {
                const int gj = 64 * q + ub + jj;
                bv[q][jj] = (bih0[gj] + bhh0[gj]) * s;
            }
        }
    } else {
        #pragma unroll
        for (int q = 0; q < 4; ++q) {
            const float s = (q == 2) ? 2.f * LOG2E : -LOG2E;
            const int g = 64 * q + 16 * wq + ln;
            #pragma unroll
            for (int ks = 0; ks < 4; ++ks) {
                const int c0 = 32 * ks + 8 * lb;
                const float* p = (c0 < 64) ? (Wih1 + g * 64 + c0)
                                           : (Whh1 + g * 64 + (c0 - 64));
                wa[q][ks] = cvt8s(p, s);
            }
            #pragma unroll
            for (int jj = 0; jj < 4; ++jj) {
                const int gj = 64 * q + ub + jj;
                bv[q][jj] = (bih1[gj] + bhh1[gj]) * s;
            }
        }
    }

    float cstA[4] = {0.f, 0.f, 0.f, 0.f};
    float cstB[4] = {0.f, 0.f, 0.f, 0.f};

    // ---- zero LDS (h states start at 0) ----
    {
        unsigned int* z = (unsigned int*)HbA;
        for (int i = tid; i < (int)(sizeof(HbA) / 4); i += 512) z[i] = 0u;
        unsigned int* z2 = (unsigned int*)HbB;
        for (int i = tid; i < (int)(sizeof(HbB) / 4); i += 512) z2[i] = 0u;
    }

    // ---- L1 x paths: lane owns x[batch][t][8lb..8lb+7] for its group ----
    const float* xbA = x + (long)(gb0 + ln) * T_STEPS * 32 + 8 * lb;
    const float* xbB = x + (long)(gb0 + 16 + ln) * T_STEPS * 32 + 8 * lb;
    f32x4 xrA0 = {0,0,0,0}, xrA1 = {0,0,0,0};
    f32x4 xrB0 = {0,0,0,0}, xrB1 = {0,0,0,0};
    if (isL1) {
        xrA0 = *(const f32x4*)(xbA);       // x_A(0)
        xrA1 = *(const f32x4*)(xbA + 4);
        xrB0 = *(const f32x4*)(xbB);       // x_B(0)
        xrB1 = *(const f32x4*)(xbB + 4);
    }
    sync_lds();

// LSTM cell update, weights pre-scaled: ei=e^{-i}, ef=e^{-f}, Eg=e^{2g}, eo=e^{-o}
// c' = [c*(1+ei)(1+Eg) + (Eg-1)(1+ef)] / ((1+ei)(1+Eg)(1+ef))
// h  = (Ec-1) / ((1+eo)(1+Ec)),  Ec = e^{2c'}
#define ACT1(A, CST, JJ)                                                       \
    {                                                                          \
        const float ei = __builtin_amdgcn_exp2f(A[0][JJ]);                     \
        const float ef = __builtin_amdgcn_exp2f(A[1][JJ]);                     \
        const float Eg = __builtin_amdgcn_exp2f(A[2][JJ]);                     \
        const float eo = __builtin_amdgcn_exp2f(A[3][JJ]);                     \
        const float ti = 1.f + ei, tf = 1.f + ef, tg = 1.f + Eg;               \
        const float pig = ti * tg;                                             \
        const float num = fmaf(Eg - 1.f, tf, CST[JJ] * pig);                   \
        const float c   = num * __builtin_amdgcn_rcpf(pig * tf);               \
        CST[JJ] = c;                                                           \
        const float Ec  = __builtin_amdgcn_exp2f(fminf((2.f * LOG2E) * c, 120.f)); \
        hh[JJ] = (_Float16)((Ec - 1.f) *                                       \
                 __builtin_amdgcn_rcpf((1.f + eo) * (1.f + Ec)));              \
    }

// one layer-1 step for one group (reads HB[P], writes h1 into HB[1-P])
#define DO_L1(J, P, HB, CST, XR0, XR1, XB)                                     \
    {                                                                          \
        const half8 bf0 = *(const half8*)&HB[P][ln][8 * lb];                   \
        const half8 bf1 = *(const half8*)&HB[P][ln][32 + 8 * lb];              \
        half8 xf;                                                              \
        _Pragma("unroll")                                                      \
        for (int j = 0; j < 4; ++j) { xf[j] = (_Float16)XR0[j]; xf[4+j] = (_Float16)XR1[j]; } \
        if ((J) + 1 < T_STEPS) {                                               \
            XR0 = *(const f32x4*)(XB + ((J) + 1) * 32);                        \
            XR1 = *(const f32x4*)(XB + ((J) + 1) * 32 + 4);                    \
        }                                                                      \
        f32x4 acc[4];                                                          \
        _Pragma("unroll")                                                      \
        for (int q = 0; q < 4; ++q)                                            \
            acc[q] = __builtin_amdgcn_mfma_f32_16x16x32_f16(wa[q][0], xf, bv[q], 0, 0, 0); \
        __builtin_amdgcn_s_setprio(1);                                         \
        _Pragma("unroll")                                                      \
        for (int q = 0; q < 4; ++q) {                                          \
            acc[q] = __builtin_amdgcn_mfma_f32_16x16x32_f16(wa[q][1], bf0, acc[q], 0, 0, 0); \
            acc[q] = __builtin_amdgcn_mfma_f32_16x16x32_f16(wa[q][2], bf1, acc[q], 0, 0, 0); \
        }                                                                      \
        __builtin_amdgcn_s_setprio(0);                                         \
        half4 hh;                                                              \
        ACT1(acc, CST, 0) ACT1(acc, CST, 1) ACT1(acc, CST, 2) ACT1(acc, CST, 3) \
        *(half4*)&HB[1 - (P)][ln][ub] = hh;                                    \
    }

// one layer-2 step for one group (reads HB[P] cols 0..127, writes h2)
#define DO_L2(J, P, HB, CST)                                                   \
    {                                                                          \
        const half8 bf0 = *(const half8*)&HB[P][ln][8 * lb];                   \
        const half8 bf1 = *(const half8*)&HB[P][ln][32 + 8 * lb];              \
        const half8 bf2 = *(const half8*)&HB[P][ln][64 + 8 * lb];              \
        const half8 bf3 = *(const half8*)&HB[P][ln][96 + 8 * lb];              \
        f32x4 acc[4];                                                          \
        __builtin_amdgcn_s_setprio(1);                                         \
        _Pragma("unroll")                                                      \
        for (int q = 0; q < 4; ++q) {                                          \
            acc[q] = __builtin_amdgcn_mfma_f32_16x16x32_f16(wa[q][0], bf0, bv[q], 0, 0, 0); \
            acc[q] = __builtin_amdgcn_mfma_f32_16x16x32_f16(wa[q][1], bf1, acc[q], 0, 0, 0); \
            acc[q] = __builtin_amdgcn_mfma_f32_16x16x32_f16(wa[q][2], bf2, acc[q], 0, 0, 0); \
            acc[q] = __builtin_amdgcn_mfma_f32_16x16x32_f16(wa[q][3], bf3, acc[q], 0, 0, 0); \
        }                                                                      \
        __builtin_amdgcn_s_setprio(0);                                         \
        half4 hh;                                                              \
        ACT1(acc, CST, 0) ACT1(acc, CST, 1) ACT1(acc, CST, 2) ACT1(acc, CST, 3) \
        *(half4*)&HB[1 - (P)][ln][64 + ub] = hh;                               \
    }

// one barrier interval: both groups advance one step (two independent chains
// per wave -> the compiler interleaves A/B instructions to fill stalls)
#define STEP(J, P)                                                             \
    do {                                                                       \
        if (isL1 && (J) < T_STEPS) {                                           \
            DO_L1(J, P, HbA, cstA, xrA0, xrA1, xbA)                            \
            DO_L1(J, P, HbB, cstB, xrB0, xrB1, xbB)                            \
        }                                                                      \
        if (!isL1 && (J) > 0) {                                                \
            DO_L2(J, P, HbA, cstA)                                             \
            DO_L2(J, P, HbB, cstB)                                             \
        }                                                                      \
        sync_lds();                                                            \
    } while (0)

    for (int jj = 0; jj < T_STEPS; jj += 2) {
        STEP(jj, 0);
        STEP(jj + 1, 1);
    }
    STEP(T_STEPS, 0);   // drain: layer 2 computes h2(255) for both groups -> Hb?[1]

    // ---- output head: out[b] = h2(255) . Wout + bout ----
    if (tid < NB) {
        const int r = tid & 15;
        float s = bout[0];
        #pragma unroll
        for (int u8 = 0; u8 < 8; ++u8) {
            const half8 hv = (tid < 16) ? *(const half8*)&HbA[1][r][64 + 8 * u8]
                                        : *(const half8*)&HbB[1][r][64 + 8 * u8];
            #pragma unroll
            for (int j = 0; j < 8; ++j)
                s += (float)hv[j] * Wout[8 * u8 + j];
        }
        out[gb0 + tid] = s;
    }
}

extern "C" void kernel_launch(void* const* d_in, const int* in_sizes, int n_in,
                              void* d_out, int out_size, void* d_ws, size_t ws_size,
                              hipStream_t stream) {
    const float* x    = (const float*)d_in[0];
    const float* Wih0 = (const float*)d_in[1];
    const float* Whh0 = (const float*)d_in[2];
    const float* bih0 = (const float*)d_in[3];
    const float* bhh0 = (const float*)d_in[4];
    const float* Wih1 = (const float*)d_in[5];
    const float* Whh1 = (const float*)d_in[6];
    const float* bih1 = (const float*)d_in[7];
    const float* bhh1 = (const float*)d_in[8];
    const float* Wout = (const float*)d_in[9];
    const float* bout = (const float*)d_in[10];

    hipLaunchKernelGGL(lstm_v8, dim3(NBLOCKS), dim3(512), 0, stream,
                       x, Wih0, Whh0, bih0, bhh0,
                       Wih1, Whh1, bih1, bhh1, Wout, bout,
                       (float*)d_out);
}

// Round 9
// 181.510 us; speedup vs baseline: 1.8284x; 1.8284x over previous
//
#include <hip/hip_runtime.h>

typedef _Float16 half8 __attribute__((ext_vector_type(8)));
typedef _Float16 half4 __attribute__((ext_vector_type(4)));
typedef float f32x4 __attribute__((ext_vector_type(4)));

#define T_STEPS 256
#define NB      16
#define NBLOCKS (4096/NB)    // 256 blocks = 1 per CU
#define LOG2E   1.4426950408889634f

// Hb row = batch (16 rows), 128 f16 cols: 0..63 = h1, 64..127 = h2.
// Row stride 256 B. All accesses XOR-swizzled: byte ^= ((row&7)<<4)
// (T2 recipe) -> 64 lanes reading 16 rows at the same col-range spread
// across bank groups; residual aliasing is 2-way (free, m136).
#define SWB(row) (((row) & 7) << 4)

__device__ __forceinline__ half8 cvt8s(const float* __restrict__ p, float s) {
    half8 r;
    #pragma unroll
    for (int j = 0; j < 8; ++j) r[j] = (_Float16)(p[j] * s);
    return r;
}

// LDS-only barrier: does NOT drain vmcnt, so global x prefetch stays in flight.
__device__ __forceinline__ void sync_lds() {
    asm volatile("s_waitcnt lgkmcnt(0)" ::: "memory");
    __builtin_amdgcn_s_barrier();
}

__global__ __launch_bounds__(512, 1)
void lstm_v9(const float* __restrict__ x,
             const float* __restrict__ Wih0, const float* __restrict__ Whh0,
             const float* __restrict__ bih0, const float* __restrict__ bhh0,
             const float* __restrict__ Wih1, const float* __restrict__ Whh1,
             const float* __restrict__ bih1, const float* __restrict__ bhh1,
             const float* __restrict__ Wout, const float* __restrict__ bout,
             float* __restrict__ out)
{
    __shared__ _Float16 Hb[2][16][128];

    const int tid  = threadIdx.x;
    const int w    = tid >> 6;
    const bool isL1 = (w < 4);          // waves 0-3: layer 1; waves 4-7: layer 2
    const int wq   = w & 3;
    const int l    = tid & 63;
    const int ln   = l & 15;            // weight row (A) / batch col (B) / Hb row
    const int lb   = l >> 4;            // k sub-block / C-row group
    const int ub   = 16 * wq + 4 * lb;  // first unit this lane's acc covers
    const int gb0  = blockIdx.x * NB;
    const int sw   = SWB(ln);           // per-lane row swizzle

    // base byte pointers for this lane's Hb rows
    char* rowR0 = (char*)&Hb[0][ln][0];
    char* rowR1 = (char*)&Hb[1][ln][0];

    // ---- weight A-fragments, register-resident, sign/scale pre-folded ----
    // gate q scale: i,f,o -> -log2e (exp2(acc) = e^{-raw}); g -> +2*log2e.
    // L1: wa[q][0] = x-slice (K 0..31), wa[q][1..2] = h1-slices; [3] unused.
    // L2: wa[q][0..3] = [h1 | h2] K-slices.
    half8 wa[4][4];
    f32x4 bv[4];
    if (isL1) {
        #pragma unroll
        for (int q = 0; q < 4; ++q) {
            const float s = (q == 2) ? 2.f * LOG2E : -LOG2E;
            const int g = 64 * q + 16 * wq + ln;
            wa[q][0] = cvt8s(Wih0 + g * 32 + 8 * lb, s);
            #pragma unroll
            for (int ks = 0; ks < 2; ++ks)
                wa[q][1 + ks] = cvt8s(Whh0 + g * 64 + 32 * ks + 8 * lb, s);
            #pragma unroll
            for (int jj = 0; jj < 4; ++jj) {
                const int gj = 64 * q + ub + jj;
                bv[q][jj] = (bih0[gj] + bhh0[gj]) * s;
            }
        }
    } else {
        #pragma unroll
        for (int q = 0; q < 4; ++q) {
            const float s = (q == 2) ? 2.f * LOG2E : -LOG2E;
            const int g = 64 * q + 16 * wq + ln;
            #pragma unroll
            for (int ks = 0; ks < 4; ++ks) {
                const int c0 = 32 * ks + 8 * lb;
                const float* p = (c0 < 64) ? (Wih1 + g * 64 + c0)
                                           : (Whh1 + g * 64 + (c0 - 64));
                wa[q][ks] = cvt8s(p, s);
            }
            #pragma unroll
            for (int jj = 0; jj < 4; ++jj) {
                const int gj = 64 * q + ub + jj;
                bv[q][jj] = (bih1[gj] + bhh1[gj]) * s;
            }
        }
    }

    float cst[4] = {0.f, 0.f, 0.f, 0.f};

    // ---- zero LDS (h states start at 0; zeros are swizzle-invariant) ----
    {
        unsigned int* z = (unsigned int*)Hb;
        for (int i = tid; i < (int)(sizeof(Hb) / 4); i += 512) z[i] = 0u;
    }

    // ---- L1 x path: lane owns x[batch gb0+ln][t][8lb..8lb+7] ----
    const float* xb = x + (long)(gb0 + ln) * T_STEPS * 32 + 8 * lb;
    f32x4 xr0 = {0.f,0.f,0.f,0.f}, xr1 = {0.f,0.f,0.f,0.f};
    if (isL1) {
        xr0 = *(const f32x4*)(xb);       // x(0)
        xr1 = *(const f32x4*)(xb + 4);
    }
    sync_lds();

// swizzled b128 read of k-slice KS from row-base RB (byte chunk 16*lb + 64*KS)
#define HRD(RB, KS) (*(const half8*)((RB) + (((16 * lb + 64 * (KS)) ^ sw))))

// LSTM cell update, weights pre-scaled: ei=e^{-i}, ef=e^{-f}, Eg=e^{2g}, eo=e^{-o}
// c' = [c*(1+ei)(1+Eg) + (Eg-1)(1+ef)] / ((1+ei)(1+Eg)(1+ef))
// h  = (Ec-1) / ((1+eo)(1+Ec)),  Ec = e^{2c'}
#define ACT1(A, JJ)                                                            \
    {                                                                          \
        const float ei = __builtin_amdgcn_exp2f(A[0][JJ]);                     \
        const float ef = __builtin_amdgcn_exp2f(A[1][JJ]);                     \
        const float Eg = __builtin_amdgcn_exp2f(A[2][JJ]);                     \
        const float eo = __builtin_amdgcn_exp2f(A[3][JJ]);                     \
        const float ti = 1.f + ei, tf = 1.f + ef, tg = 1.f + Eg;               \
        const float pig = ti * tg;                                             \
        const float num = fmaf(Eg - 1.f, tf, cst[JJ] * pig);                   \
        const float c   = num * __builtin_amdgcn_rcpf(pig * tf);               \
        cst[JJ] = c;                                                           \
        const float Ec  = __builtin_amdgcn_exp2f(fminf((2.f * LOG2E) * c, 120.f)); \
        hh[JJ] = (_Float16)((Ec - 1.f) *                                       \
                 __builtin_amdgcn_rcpf((1.f + eo) * (1.f + Ec)));              \
    }

#define STEP(J, P)                                                             \
    do {                                                                       \
        char* rdP = (P) ? rowR1 : rowR0;                                       \
        char* wrP = (P) ? rowR0 : rowR1;                                       \
        if (isL1 && (J) < T_STEPS) {                                           \
            /* issue h1(J-1) reads first (ds latency covered by x-MFMAs) */    \
            const half8 bf0 = HRD(rdP, 0);                                     \
            const half8 bf1 = HRD(rdP, 1);                                     \
            /* consume x(J) from regs, then immediately prefetch x(J+1) */     \
            half8 xf;                                                          \
            _Pragma("unroll")                                                  \
            for (int j = 0; j < 4; ++j) { xf[j] = (_Float16)xr0[j]; xf[4+j] = (_Float16)xr1[j]; } \
            if ((J) + 1 < T_STEPS) {                                           \
                xr0 = *(const f32x4*)(xb + ((J) + 1) * 32);                    \
                xr1 = *(const f32x4*)(xb + ((J) + 1) * 32 + 4);                \
            }                                                                  \
            f32x4 acc[4];                                                      \
            _Pragma("unroll")                                                  \
            for (int q = 0; q < 4; ++q)                                        \
                acc[q] = __builtin_amdgcn_mfma_f32_16x16x32_f16(wa[q][0], xf, bv[q], 0, 0, 0); \
            _Pragma("unroll")                                                  \
            for (int q = 0; q < 4; ++q) {                                      \
                acc[q] = __builtin_amdgcn_mfma_f32_16x16x32_f16(wa[q][1], bf0, acc[q], 0, 0, 0); \
                acc[q] = __builtin_amdgcn_mfma_f32_16x16x32_f16(wa[q][2], bf1, acc[q], 0, 0, 0); \
            }                                                                  \
            half4 hh;                                                          \
            ACT1(acc, 0) ACT1(acc, 1) ACT1(acc, 2) ACT1(acc, 3)                \
            *(half4*)(wrP + ((2 * ub) ^ sw)) = hh;                             \
        }                                                                      \
        if (!isL1 && (J) > 0) {                                                \
            const half8 bf0 = HRD(rdP, 0);                                     \
            const half8 bf1 = HRD(rdP, 1);                                     \
            const half8 bf2 = HRD(rdP, 2);                                     \
            const half8 bf3 = HRD(rdP, 3);                                     \
            f32x4 acc[4];                                                      \
            _Pragma("unroll")                                                  \
            for (int q = 0; q < 4; ++q) {                                      \
                acc[q] = __builtin_amdgcn_mfma_f32_16x16x32_f16(wa[q][0], bf0, bv[q], 0, 0, 0); \
                acc[q] = __builtin_amdgcn_mfma_f32_16x16x32_f16(wa[q][1], bf1, acc[q], 0, 0, 0); \
                acc[q] = __builtin_amdgcn_mfma_f32_16x16x32_f16(wa[q][2], bf2, acc[q], 0, 0, 0); \
                acc[q] = __builtin_amdgcn_mfma_f32_16x16x32_f16(wa[q][3], bf3, acc[q], 0, 0, 0); \
            }                                                                  \
            half4 hh;                                                          \
            ACT1(acc, 0) ACT1(acc, 1) ACT1(acc, 2) ACT1(acc, 3)                \
            *(half4*)(wrP + ((128 + 2 * ub) ^ sw)) = hh;                       \
        }                                                                      \
        sync_lds();                                                            \
    } while (0)

    for (int jj = 0; jj < T_STEPS; jj += 2) {
        STEP(jj, 0);
        STEP(jj + 1, 1);
    }
    STEP(T_STEPS, 0);   // drain: layer 2 computes h2(255) -> Hb[1]

    // ---- output head: out[b] = h2(255) . Wout + bout (swizzled reads) ----
    if (tid < NB) {
        const char* rowb = (const char*)&Hb[1][tid][0];
        const int swr = SWB(tid);
        float s = bout[0];
        #pragma unroll
        for (int u8 = 0; u8 < 8; ++u8) {
            const half8 hv = *(const half8*)(rowb + ((128 + 16 * u8) ^ swr));
            #pragma unroll
            for (int j = 0; j < 8; ++j)
                s += (float)hv[j] * Wout[8 * u8 + j];
        }
        out[gb0 + tid] = s;
    }
}

extern "C" void kernel_launch(void* const* d_in, const int* in_sizes, int n_in,
                              void* d_out, int out_size, void* d_ws, size_t ws_size,
                              hipStream_t stream) {
    const float* x    = (const float*)d_in[0];
    const float* Wih0 = (const float*)d_in[1];
    const float* Whh0 = (const float*)d_in[2];
    const float* bih0 = (const float*)d_in[3];
    const float* bhh0 = (const float*)d_in[4];
    const float* Wih1 = (const float*)d_in[5];
    const float* Whh1 = (const float*)d_in[6];
    const float* bih1 = (const float*)d_in[7];
    const float* bhh1 = (const float*)d_in[8];
    const float* Wout = (const float*)d_in[9];
    const float* bout = (const float*)d_in[10];

    hipLaunchKernelGGL(lstm_v9, dim3(NBLOCKS), dim3(512), 0, stream,
                       x, Wih0, Whh0, bih0, bhh0,
                       Wih1, Whh1, bih1, bhh1, Wout, bout,
                       (float*)d_out);
}